// Round 4
// baseline (7397.565 us; speedup 1.0000x reference)
//
#include <hip/hip_runtime.h>
#include <hip/hip_cooperative_groups.h>
#include <math.h>

namespace cg = cooperative_groups;

#define SEQ   16384
#define DIM   1024
#define WU    32                    // warm-up steps (32 empirically proven r1/r2)
#define CHUNK 32
#define NCH   (SEQ / CHUNK)         // 512 chunks per direction
#define NSTR  (2 * NCH)             // 1024 parallel streams
#define NSTEP (WU + CHUNK)          // 64 batched steps

typedef __attribute__((ext_vector_type(8)))  short bf16x8;
typedef __attribute__((ext_vector_type(16))) float f32x16;

__device__ __forceinline__ unsigned short f2bf(float f) {
    unsigned int x = __float_as_uint(f);
    unsigned int r = (x + 0x7fffu + ((x >> 16) & 1u)) >> 16;
    return (unsigned short)r;
}
__device__ __forceinline__ float bf2f(unsigned short u) {
    return __uint_as_float(((unsigned int)u) << 16);
}

// ---------------------------------------------------------------------------
// W (KxN fp32) -> n-major NxK bf16 hi/lo pair (Wx and Wh).
// ---------------------------------------------------------------------------
__global__ __launch_bounds__(256)
void wsplit_kernel(const float* __restrict__ W,
                   unsigned short* __restrict__ WTh,
                   unsigned short* __restrict__ WTl)
{
    const int bk = blockIdx.x & 15, bn = blockIdx.x >> 4;
    const int k0 = bk * 64, n0 = bn * 64;
    const int tid = threadIdx.x;
    __shared__ float T[64][65];
#pragma unroll
    for (int it = 0; it < 4; ++it) {
        int f = tid + 256 * it;
        int r = f >> 4;
        int c4 = (f & 15) << 2;
        const float4 v = *reinterpret_cast<const float4*>(
            &W[(size_t)(k0 + r) * DIM + n0 + c4]);
        T[r][c4 + 0] = v.x; T[r][c4 + 1] = v.y;
        T[r][c4 + 2] = v.z; T[r][c4 + 3] = v.w;
    }
    __syncthreads();
#pragma unroll
    for (int it = 0; it < 4; ++it) {
        int f  = tid + 256 * it;
        int rn = f >> 4;
        int c4 = (f & 15) << 2;
        float vv[4] = {T[c4 + 0][rn], T[c4 + 1][rn], T[c4 + 2][rn], T[c4 + 3][rn]};
        ushort4 hi, lo;
        unsigned short h[4], l[4];
#pragma unroll
        for (int j = 0; j < 4; ++j) {
            h[j] = f2bf(vv[j]);
            l[j] = f2bf(vv[j] - bf2f(h[j]));
        }
        hi.x = h[0]; hi.y = h[1]; hi.z = h[2]; hi.w = h[3];
        lo.x = l[0]; lo.y = l[1]; lo.z = l[2]; lo.w = l[3];
        *reinterpret_cast<ushort4*>(&WTh[(size_t)(n0 + rn) * DIM + k0 + c4]) = hi;
        *reinterpret_cast<ushort4*>(&WTl[(size_t)(n0 + rn) * DIM + k0 + c4]) = lo;
    }
}

// ---------------------------------------------------------------------------
// x (fp32) -> xh/xl bf16 hi/lo. Memory-bound.
// ---------------------------------------------------------------------------
__global__ __launch_bounds__(256)
void xsplit_kernel(const float* __restrict__ x,
                   unsigned short* __restrict__ xh,
                   unsigned short* __restrict__ xl)
{
    const int N4 = SEQ * DIM / 4;
    for (int idx = blockIdx.x * 256 + threadIdx.x; idx < N4; idx += gridDim.x * 256) {
        const float4 v = reinterpret_cast<const float4*>(x)[idx];
        ushort4 h, l;
        h.x = f2bf(v.x); l.x = f2bf(v.x - bf2f(h.x));
        h.y = f2bf(v.y); l.y = f2bf(v.y - bf2f(h.y));
        h.z = f2bf(v.z); l.z = f2bf(v.z - bf2f(h.z));
        h.w = f2bf(v.w); l.w = f2bf(v.w - bf2f(h.w));
        reinterpret_cast<ushort4*>(xh)[idx] = h;
        reinterpret_cast<ushort4*>(xl)[idx] = l;
    }
}

// ---------------------------------------------------------------------------
// xproj = x @ Wx + b, MFMA 32x32x16, 3-term hi/lo (fp32-accurate).
// REBUILT vs r3 (r3 spilled: VGPR=68 w/ 64 acc + 32 prefetch -> 958MB scratch
// write traffic). Block 128x64, 4 waves (2m x 2n), wave 64x32 -> acc = 2x16
// = 32 regs; prefetch = 6 uint4 = 24 regs; ~90 VGPR total, no spill.
// BK=32, single-buffer LDS + reg prefetch. Grid 2048, bm-major per XCD:
// A fetched ~once (64MB), B refetched 8x (32MB) -> ~130MB total HBM.
// ---------------------------------------------------------------------------
__global__ __launch_bounds__(256)
void xproj_mfma(const unsigned short* __restrict__ xh,
                const unsigned short* __restrict__ xl,
                const unsigned short* __restrict__ WxTh,
                const unsigned short* __restrict__ WxTl,
                const float* __restrict__ b, float* __restrict__ xp)
{
    // bm-major XCD swizzle: XCD x gets gb in [x*256, x*256+256) -> bm band
    const int gb = (blockIdx.x & 7) * 256 + (blockIdx.x >> 3);
    const int bm = gb >> 4, bn = gb & 15;         // bm 0..127, bn 0..15
    const int row0 = bm * 128, col0 = bn * 64;
    const int tid = threadIdx.x, lane = tid & 63, w = tid >> 6;
    const int wm = w >> 1, wn = w & 1;

    __shared__ unsigned short Ah[128][40], Al[128][40];
    __shared__ unsigned short Bh[64][40],  Bl[64][40];

    f32x16 acc[2];
#pragma unroll
    for (int mi = 0; mi < 2; ++mi)
#pragma unroll
        for (int r = 0; r < 16; ++r) acc[mi][r] = 0.f;

    // staging maps: A 128x32 (2 uint4/thread/array), B 64x32 (1 uint4/thread/array)
    const int ar = tid >> 1, ak = (tid & 1) * 16;
    const int br = tid >> 2, bk = (tid & 3) * 8;
    const size_t ga = (size_t)(row0 + ar) * DIM + ak;
    const size_t gbb = (size_t)(col0 + br) * DIM + bk;

    uint4 pah0, pah1, pal0, pal1, pbh, pbl;
#define XLOAD(k0_) do {                                                        \
        pah0 = *reinterpret_cast<const uint4*>(xh   + ga  + (k0_));            \
        pah1 = *reinterpret_cast<const uint4*>(xh   + ga  + (k0_) + 8);        \
        pal0 = *reinterpret_cast<const uint4*>(xl   + ga  + (k0_));            \
        pal1 = *reinterpret_cast<const uint4*>(xl   + ga  + (k0_) + 8);        \
        pbh  = *reinterpret_cast<const uint4*>(WxTh + gbb + (k0_));            \
        pbl  = *reinterpret_cast<const uint4*>(WxTl + gbb + (k0_));            \
    } while (0)

    XLOAD(0);
    const int am0 = wm * 64 + (lane & 31), am1 = am0 + 32;
    const int bn0 = wn * 32 + (lane & 31);
    const int kh  = (lane >> 5) * 8;

    for (int kt = 0; kt < 32; ++kt) {
        __syncthreads();                          // prev-iter reads done
        *reinterpret_cast<uint4*>(&Ah[ar][ak])     = pah0;
        *reinterpret_cast<uint4*>(&Ah[ar][ak + 8]) = pah1;
        *reinterpret_cast<uint4*>(&Al[ar][ak])     = pal0;
        *reinterpret_cast<uint4*>(&Al[ar][ak + 8]) = pal1;
        *reinterpret_cast<uint4*>(&Bh[br][bk])     = pbh;
        *reinterpret_cast<uint4*>(&Bl[br][bk])     = pbl;
        __syncthreads();
        if (kt < 31) XLOAD((size_t)(kt + 1) * 32);
#pragma unroll
        for (int ks = 0; ks < 2; ++ks) {
            const int ko = ks * 16 + kh;
            bf16x8 a0h = *reinterpret_cast<const bf16x8*>(&Ah[am0][ko]);
            bf16x8 a1h = *reinterpret_cast<const bf16x8*>(&Ah[am1][ko]);
            bf16x8 a0l = *reinterpret_cast<const bf16x8*>(&Al[am0][ko]);
            bf16x8 a1l = *reinterpret_cast<const bf16x8*>(&Al[am1][ko]);
            bf16x8 bh  = *reinterpret_cast<const bf16x8*>(&Bh[bn0][ko]);
            bf16x8 bl  = *reinterpret_cast<const bf16x8*>(&Bl[bn0][ko]);
            acc[0] = __builtin_amdgcn_mfma_f32_32x32x16_bf16(a0h, bh, acc[0], 0, 0, 0);
            acc[1] = __builtin_amdgcn_mfma_f32_32x32x16_bf16(a1h, bh, acc[1], 0, 0, 0);
            acc[0] = __builtin_amdgcn_mfma_f32_32x32x16_bf16(a0h, bl, acc[0], 0, 0, 0);
            acc[1] = __builtin_amdgcn_mfma_f32_32x32x16_bf16(a1h, bl, acc[1], 0, 0, 0);
            acc[0] = __builtin_amdgcn_mfma_f32_32x32x16_bf16(a0l, bh, acc[0], 0, 0, 0);
            acc[1] = __builtin_amdgcn_mfma_f32_32x32x16_bf16(a1l, bh, acc[1], 0, 0, 0);
        }
    }
#undef XLOAD

    // C layout (m74/m101): col = lane&31, row = (r&3) + 8*(r>>2) + 4*(lane>>5)
    const int rbase = 4 * (lane >> 5);
    const int col = col0 + wn * 32 + (lane & 31);
    const float bb = b[col];
#pragma unroll
    for (int mi = 0; mi < 2; ++mi) {
#pragma unroll
        for (int r = 0; r < 16; ++r) {
            const int row = row0 + wm * 64 + mi * 32 + (r & 3) + 8 * (r >> 2) + rbase;
            xp[(size_t)row * DIM + col] = acc[mi][r] + bb;
        }
    }
}

// ---------------------------------------------------------------------------
// Persistent cooperative step kernel: all 64 recurrence steps in ONE dispatch.
// Per-step body is r3's proven step32 (absmax 0.0078); grid.sync() between
// steps replaces 64 kernel launches (the measured ~10us/step overhead).
// __threadfence() release/acquire around sync handles cross-XCD L2 for the
// H ping-pong. Grid 256 x 512thr (co-resident: 55KB LDS, ~80 VGPR).
// ---------------------------------------------------------------------------
__global__ __launch_bounds__(512)
void step_persist(unsigned short* __restrict__ Ha,   // read at even i
                  unsigned short* __restrict__ Hb,   // read at odd i
                  const float* __restrict__ xp,
                  const unsigned short* __restrict__ WhTh,
                  const unsigned short* __restrict__ WhTl,
                  float* __restrict__ out)
{
    cg::grid_group grid = cg::this_grid();

    const int bid = ((blockIdx.x & 7) << 5) | (blockIdx.x >> 3);  // XCD swizzle
    const int bm = bid & 15, bn = bid >> 4;
    const int row0 = bm * 64, col0 = bn * 64;
    const int tid = threadIdx.x, lane = tid & 63, w = tid >> 6;
    const int g = w >> 2, wi = w & 3, wm = wi >> 1, wn = wi & 1;

    __shared__ unsigned short A[2][64][72];
    __shared__ unsigned short Bh[2][64][72];
    __shared__ unsigned short Bl[2][64][72];   // aliased as Red after k-loop

    const int sr = tid >> 3;
    const int sc = (tid & 7) * 8;
    const size_t gA = (size_t)(row0 + sr) * DIM + sc;
    const size_t gB = (size_t)(col0 + sr) * DIM + sc;

    const int ar = wm * 32 + (lane & 31);
    const int br = wn * 32 + (lane & 31);
    const int kh = (lane >> 5) * 8;
    float* Red = reinterpret_cast<float*>(&Bl[0][0][0]);

    for (int i = 0; i < NSTEP; ++i) {
        const unsigned short* Hin = (i & 1) ? Hb : Ha;
        unsigned short*      Hout = (i & 1) ? Ha : Hb;

        f32x16 acc;
#pragma unroll
        for (int r = 0; r < 16; ++r) acc[r] = 0.f;

        uint4 pa0, pa1, pbh0, pbh1, pbl0, pbl1;
#define SLOAD(it_) do {                                                          \
        const size_t k0_ = (size_t)(it_) * 64, k1_ = (size_t)((it_) + 8) * 64;   \
        pa0  = *reinterpret_cast<const uint4*>(Hin  + gA + k0_);                 \
        pa1  = *reinterpret_cast<const uint4*>(Hin  + gA + k1_);                 \
        pbh0 = *reinterpret_cast<const uint4*>(WhTh + gB + k0_);                 \
        pbh1 = *reinterpret_cast<const uint4*>(WhTh + gB + k1_);                 \
        pbl0 = *reinterpret_cast<const uint4*>(WhTl + gB + k0_);                 \
        pbl1 = *reinterpret_cast<const uint4*>(WhTl + gB + k1_);                 \
    } while (0)

        SLOAD(0);
        for (int it = 0; it < 8; ++it) {
            __syncthreads();
            *reinterpret_cast<uint4*>(&A[0][sr][sc])  = pa0;
            *reinterpret_cast<uint4*>(&A[1][sr][sc])  = pa1;
            *reinterpret_cast<uint4*>(&Bh[0][sr][sc]) = pbh0;
            *reinterpret_cast<uint4*>(&Bh[1][sr][sc]) = pbh1;
            *reinterpret_cast<uint4*>(&Bl[0][sr][sc]) = pbl0;
            *reinterpret_cast<uint4*>(&Bl[1][sr][sc]) = pbl1;
            __syncthreads();
            if (it < 7) SLOAD(it + 1);
#pragma unroll
            for (int ks = 0; ks < 4; ++ks) {
                const int ko = ks * 16 + kh;
                bf16x8 a  = *reinterpret_cast<const bf16x8*>(&A[g][ar][ko]);
                bf16x8 bh = *reinterpret_cast<const bf16x8*>(&Bh[g][br][ko]);
                bf16x8 bl = *reinterpret_cast<const bf16x8*>(&Bl[g][br][ko]);
                acc = __builtin_amdgcn_mfma_f32_32x32x16_bf16(a, bh, acc, 0, 0, 0);
                acc = __builtin_amdgcn_mfma_f32_32x32x16_bf16(a, bl, acc, 0, 0, 0);
            }
        }
#undef SLOAD

        // combine K halves: group1 -> LDS, group0 adds + epilogue
        __syncthreads();
        if (g == 1) {
#pragma unroll
            for (int r = 0; r < 16; ++r) Red[(wi * 16 + r) * 64 + lane] = acc[r];
        }
        __syncthreads();
        if (g == 0) {
            const int col = col0 + wn * 32 + (lane & 31);
            const int rbase = 4 * (lane >> 5);
#pragma unroll
            for (int r = 0; r < 16; ++r) {
                const float v = acc[r] + Red[(wi * 16 + r) * 64 + lane];
                const int srow = (r & 3) + 8 * (r >> 2) + rbase;
                const int s = row0 + wm * 32 + srow;
                const int dir = s >> 9;
                const int c   = s & 511;
                const int t   = c * CHUNK + (i - WU);
                float h = 0.f;
                if (t >= 0) {
                    const int xrow = dir ? (SEQ - 1 - t) : t;
                    h = tanhf(v + xp[(size_t)xrow * DIM + col]);
                }
                Hout[(size_t)s * DIM + col] = f2bf(h);
                if (i >= WU) {
                    const int orow = dir ? (SEQ + t) : t;
                    out[(size_t)orow * DIM + col] = h;
                }
            }
        }
        __threadfence();      // release H writes (cross-XCD)
        grid.sync();
        __threadfence();      // acquire: invalidate stale L2 lines of H
    }
}

// ---------------------------------------------------------------------------
extern "C" void kernel_launch(void* const* d_in, const int* in_sizes, int n_in,
                              void* d_out, int out_size, void* d_ws, size_t ws_size,
                              hipStream_t stream)
{
    (void)in_sizes; (void)n_in; (void)out_size; (void)ws_size;
    const float* x  = (const float*)d_in[0];
    const float* Wx = (const float*)d_in[1];
    const float* Wh = (const float*)d_in[2];
    const float* b  = (const float*)d_in[3];
    float* out = (float*)d_out;

    char* ws = (char*)d_ws;
    const size_t MB = 1ull << 20;
    float*          xp   = (float*)ws;                        // [0, 64MB)
    unsigned short* WxTh = (unsigned short*)(ws + 64 * MB);
    unsigned short* WxTl = (unsigned short*)(ws + 66 * MB);
    unsigned short* WhTh = (unsigned short*)(ws + 68 * MB);
    unsigned short* WhTl = (unsigned short*)(ws + 70 * MB);
    unsigned short* H0   = (unsigned short*)(ws + 72 * MB);
    unsigned short* H1   = (unsigned short*)(ws + 74 * MB);   // end 76MB

    // x hi/lo lives in d_out's first 64MB; consumed by xproj before steps
    // overwrite it (stream-ordered).
    unsigned short* xh = (unsigned short*)d_out;
    unsigned short* xl = xh + (size_t)SEQ * DIM;

    hipLaunchKernelGGL(wsplit_kernel, dim3(256), dim3(256), 0, stream, Wx, WxTh, WxTl);
    hipLaunchKernelGGL(wsplit_kernel, dim3(256), dim3(256), 0, stream, Wh, WhTh, WhTl);
    hipLaunchKernelGGL(xsplit_kernel, dim3(2048), dim3(256), 0, stream, x, xh, xl);
    hipLaunchKernelGGL(xproj_mfma, dim3(2048), dim3(256), 0, stream,
                       xh, xl, WxTh, WxTl, b, xp);
    hipMemsetAsync(H0, 0, 2 * MB, stream);

    void* args[] = {(void*)&H0, (void*)&H1, (void*)&xp,
                    (void*)&WhTh, (void*)&WhTl, (void*)&out};
    hipLaunchCooperativeKernel((void*)step_persist, dim3(256), dim3(512),
                               args, 0, stream);
}

// Round 5
// 1551.303 us; speedup vs baseline: 4.7686x; 4.7686x over previous
//
#include <hip/hip_runtime.h>
#include <math.h>

#define SEQ   16384
#define DIM   1024
#define WU    32                    // warm-up steps (empirically proven r1/r2)
#define CHUNK 32
#define NCH   (SEQ / CHUNK)         // 512 chunks per direction
#define NSTR  (2 * NCH)             // 1024 parallel streams
#define NSTEP (WU + CHUNK)          // 64 batched steps

typedef __attribute__((ext_vector_type(8)))  short bf16x8;
typedef __attribute__((ext_vector_type(4)))  float f32x4;
typedef __attribute__((ext_vector_type(16))) float f32x16;

__device__ __forceinline__ unsigned short f2bf(float f) {
    unsigned int x = __float_as_uint(f);
    unsigned int r = (x + 0x7fffu + ((x >> 16) & 1u)) >> 16;
    return (unsigned short)r;
}
__device__ __forceinline__ float bf2f(unsigned short u) {
    return __uint_as_float(((unsigned int)u) << 16);
}

// ---------------------------------------------------------------------------
// W (KxN fp32) -> n-major NxK bf16 hi/lo pair (Wx and Wh).
// ---------------------------------------------------------------------------
__global__ __launch_bounds__(256)
void wsplit_kernel(const float* __restrict__ W,
                   unsigned short* __restrict__ WTh,
                   unsigned short* __restrict__ WTl)
{
    const int bk = blockIdx.x & 15, bn = blockIdx.x >> 4;
    const int k0 = bk * 64, n0 = bn * 64;
    const int tid = threadIdx.x;
    __shared__ float T[64][65];
#pragma unroll
    for (int it = 0; it < 4; ++it) {
        int f = tid + 256 * it;
        int r = f >> 4;
        int c4 = (f & 15) << 2;
        const float4 v = *reinterpret_cast<const float4*>(
            &W[(size_t)(k0 + r) * DIM + n0 + c4]);
        T[r][c4 + 0] = v.x; T[r][c4 + 1] = v.y;
        T[r][c4 + 2] = v.z; T[r][c4 + 3] = v.w;
    }
    __syncthreads();
#pragma unroll
    for (int it = 0; it < 4; ++it) {
        int f  = tid + 256 * it;
        int rn = f >> 4;
        int c4 = (f & 15) << 2;
        float vv[4] = {T[c4 + 0][rn], T[c4 + 1][rn], T[c4 + 2][rn], T[c4 + 3][rn]};
        ushort4 hi, lo;
        unsigned short h[4], l[4];
#pragma unroll
        for (int j = 0; j < 4; ++j) {
            h[j] = f2bf(vv[j]);
            l[j] = f2bf(vv[j] - bf2f(h[j]));
        }
        hi.x = h[0]; hi.y = h[1]; hi.z = h[2]; hi.w = h[3];
        lo.x = l[0]; lo.y = l[1]; lo.z = l[2]; lo.w = l[3];
        *reinterpret_cast<ushort4*>(&WTh[(size_t)(n0 + rn) * DIM + k0 + c4]) = hi;
        *reinterpret_cast<ushort4*>(&WTl[(size_t)(n0 + rn) * DIM + k0 + c4]) = lo;
    }
}

// ---------------------------------------------------------------------------
// x (fp32) -> xh/xl bf16 hi/lo. Memory-bound.
// ---------------------------------------------------------------------------
__global__ __launch_bounds__(256)
void xsplit_kernel(const float* __restrict__ x,
                   unsigned short* __restrict__ xh,
                   unsigned short* __restrict__ xl)
{
    const int N4 = SEQ * DIM / 4;
    for (int idx = blockIdx.x * 256 + threadIdx.x; idx < N4; idx += gridDim.x * 256) {
        const float4 v = reinterpret_cast<const float4*>(x)[idx];
        ushort4 h, l;
        h.x = f2bf(v.x); l.x = f2bf(v.x - bf2f(h.x));
        h.y = f2bf(v.y); l.y = f2bf(v.y - bf2f(h.y));
        h.z = f2bf(v.z); l.z = f2bf(v.z - bf2f(h.z));
        h.w = f2bf(v.w); l.w = f2bf(v.w - bf2f(h.w));
        reinterpret_cast<ushort4*>(xh)[idx] = h;
        reinterpret_cast<ushort4*>(xl)[idx] = l;
    }
}

// ---------------------------------------------------------------------------
// xproj = x @ Wx + b, MFMA 32x32x16, 3-term hi/lo (fp32-accurate).
// (r4 rebuild of the r3 spiller: acc 32 regs, prefetch 24 regs, no spill.)
// ---------------------------------------------------------------------------
__global__ __launch_bounds__(256)
void xproj_mfma(const unsigned short* __restrict__ xh,
                const unsigned short* __restrict__ xl,
                const unsigned short* __restrict__ WxTh,
                const unsigned short* __restrict__ WxTl,
                const float* __restrict__ b, float* __restrict__ xp)
{
    const int gb = (blockIdx.x & 7) * 256 + (blockIdx.x >> 3);
    const int bm = gb >> 4, bn = gb & 15;
    const int row0 = bm * 128, col0 = bn * 64;
    const int tid = threadIdx.x, lane = tid & 63, w = tid >> 6;
    const int wm = w >> 1, wn = w & 1;

    __shared__ unsigned short Ah[128][40], Al[128][40];
    __shared__ unsigned short Bh[64][40],  Bl[64][40];

    f32x16 acc[2];
#pragma unroll
    for (int mi = 0; mi < 2; ++mi)
#pragma unroll
        for (int r = 0; r < 16; ++r) acc[mi][r] = 0.f;

    const int ar = tid >> 1, ak = (tid & 1) * 16;
    const int br = tid >> 2, bk = (tid & 3) * 8;
    const size_t ga = (size_t)(row0 + ar) * DIM + ak;
    const size_t gbb = (size_t)(col0 + br) * DIM + bk;

    uint4 pah0, pah1, pal0, pal1, pbh, pbl;
#define XLOAD(k0_) do {                                                        \
        pah0 = *reinterpret_cast<const uint4*>(xh   + ga  + (k0_));            \
        pah1 = *reinterpret_cast<const uint4*>(xh   + ga  + (k0_) + 8);        \
        pal0 = *reinterpret_cast<const uint4*>(xl   + ga  + (k0_));            \
        pal1 = *reinterpret_cast<const uint4*>(xl   + ga  + (k0_) + 8);        \
        pbh  = *reinterpret_cast<const uint4*>(WxTh + gbb + (k0_));            \
        pbl  = *reinterpret_cast<const uint4*>(WxTl + gbb + (k0_));            \
    } while (0)

    XLOAD(0);
    const int am0 = wm * 64 + (lane & 31), am1 = am0 + 32;
    const int bn0 = wn * 32 + (lane & 31);
    const int kh  = (lane >> 5) * 8;

    for (int kt = 0; kt < 32; ++kt) {
        __syncthreads();
        *reinterpret_cast<uint4*>(&Ah[ar][ak])     = pah0;
        *reinterpret_cast<uint4*>(&Ah[ar][ak + 8]) = pah1;
        *reinterpret_cast<uint4*>(&Al[ar][ak])     = pal0;
        *reinterpret_cast<uint4*>(&Al[ar][ak + 8]) = pal1;
        *reinterpret_cast<uint4*>(&Bh[br][bk])     = pbh;
        *reinterpret_cast<uint4*>(&Bl[br][bk])     = pbl;
        __syncthreads();
        if (kt < 31) XLOAD((size_t)(kt + 1) * 32);
#pragma unroll
        for (int ks = 0; ks < 2; ++ks) {
            const int ko = ks * 16 + kh;
            bf16x8 a0h = *reinterpret_cast<const bf16x8*>(&Ah[am0][ko]);
            bf16x8 a1h = *reinterpret_cast<const bf16x8*>(&Ah[am1][ko]);
            bf16x8 a0l = *reinterpret_cast<const bf16x8*>(&Al[am0][ko]);
            bf16x8 a1l = *reinterpret_cast<const bf16x8*>(&Al[am1][ko]);
            bf16x8 bh  = *reinterpret_cast<const bf16x8*>(&Bh[bn0][ko]);
            bf16x8 bl  = *reinterpret_cast<const bf16x8*>(&Bl[bn0][ko]);
            acc[0] = __builtin_amdgcn_mfma_f32_32x32x16_bf16(a0h, bh, acc[0], 0, 0, 0);
            acc[1] = __builtin_amdgcn_mfma_f32_32x32x16_bf16(a1h, bh, acc[1], 0, 0, 0);
            acc[0] = __builtin_amdgcn_mfma_f32_32x32x16_bf16(a0h, bl, acc[0], 0, 0, 0);
            acc[1] = __builtin_amdgcn_mfma_f32_32x32x16_bf16(a1h, bl, acc[1], 0, 0, 0);
            acc[0] = __builtin_amdgcn_mfma_f32_32x32x16_bf16(a0l, bh, acc[0], 0, 0, 0);
            acc[1] = __builtin_amdgcn_mfma_f32_32x32x16_bf16(a1l, bh, acc[1], 0, 0, 0);
        }
    }
#undef XLOAD

    const int rbase = 4 * (lane >> 5);
    const int col = col0 + wn * 32 + (lane & 31);
    const float bb = b[col];
#pragma unroll
    for (int mi = 0; mi < 2; ++mi) {
#pragma unroll
        for (int r = 0; r < 16; ++r) {
            const int row = row0 + wm * 64 + mi * 32 + (r & 3) + 8 * (r >> 2) + rbase;
            xp[(size_t)row * DIM + col] = acc[mi][r] + bb;
        }
    }
}

// ---------------------------------------------------------------------------
// Persistent step kernel v2. Key differences vs r4's failed version:
//   * Wh hi/lo panel (32 cols x 1024 k = 129KB) loaded into LDS ONCE and kept
//     for all 64 steps -> the per-step L2 invalidate can't evict it (r4's
//     FETCH 9.6MB/step was Wh refetch from HBM after each grid.sync fence).
//   * custom 2-level atomic barrier (relaxed adds + single release/acquire
//     __threadfence per block) instead of grid.sync.
// Block: 128 streams x 32 cols; bm = blockIdx&7 (XCD-shared H slab),
// bn = blockIdx>>3. 8 waves = 4m x 2n, wave 32m x 16n, mfma 16x16x32,
// full K per wave (no reduce). A double-buffered BK=32.
// LDS: B 2x64.5KB + A 20KB = 152.6KB -> 1 block/CU, co-resident grid 256.
// ---------------------------------------------------------------------------
#define BKP 32

__global__ __launch_bounds__(512)
void step_persist2(unsigned short* __restrict__ Ha,
                   unsigned short* __restrict__ Hb,
                   const float* __restrict__ xp,
                   const unsigned short* __restrict__ WhTh,
                   const unsigned short* __restrict__ WhTl,
                   float* __restrict__ out,
                   unsigned int* bar)
{
    const int row0 = (blockIdx.x & 7) * 128;      // H slab shared per XCD
    const int col0 = (blockIdx.x >> 3) * 32;
    const int grp  = blockIdx.x & 15;
    const int tid = threadIdx.x, lane = tid & 63, w = tid >> 6;
    const int wm = w >> 1, wn = w & 1;            // wave tile 32m x 16n

    __shared__ unsigned short Bh[32][1032], Bl[32][1032];   // persistent
    __shared__ unsigned short A[2][128][40];                 // double buffer

    // ---- load Wh panel into LDS once ----
    {
        const int c  = tid >> 4;                  // 0..31
        const int kb = (tid & 15) * 64;           // 64 bf16 per thread per row
#pragma unroll
        for (int j = 0; j < 8; ++j) {
            const uint4 vh = *reinterpret_cast<const uint4*>(
                &WhTh[(size_t)(col0 + c) * DIM + kb + j * 8]);
            const uint4 vl = *reinterpret_cast<const uint4*>(
                &WhTl[(size_t)(col0 + c) * DIM + kb + j * 8]);
            *reinterpret_cast<uint4*>(&Bh[c][kb + j * 8]) = vh;
            *reinterpret_cast<uint4*>(&Bl[c][kb + j * 8]) = vl;
        }
    }
    __syncthreads();

    // per-thread constant maps
    const int sar = tid >> 2;                     // A staging row 0..127
    const int sak = (tid & 3) * 8;                // A staging k chunk
    const int colg = col0 + wn * 16 + (lane & 15);
    const int ka   = (lane >> 4) * 8;             // frag k offset
    const int am0  = wm * 32 + (lane & 15);       // frag A rows
    const int am1  = am0 + 16;
    const int bcol = wn * 16 + (lane & 15);       // frag B row (col of Wh^T)

    for (int i = 0; i < NSTEP; ++i) {
        const unsigned short* Hin = (i & 1) ? Hb : Ha;
        unsigned short*      Hout = (i & 1) ? Ha : Hb;

        // ---- xp prefetch (latency hidden under the K loop) ----
        float xpv[2][4];
        int   tt[2][4];
#pragma unroll
        for (int f = 0; f < 2; ++f)
#pragma unroll
            for (int r = 0; r < 4; ++r) {
                const int s = row0 + wm * 32 + f * 16 + (lane >> 4) * 4 + r;
                const int t = (s & 511) * CHUNK + (i - WU);
                tt[f][r] = t;
                const int xrow = (t < 0) ? 0 : ((s >> 9) ? (SEQ - 1 - t) : t);
                xpv[f][r] = xp[(size_t)xrow * DIM + colg];
            }

        f32x4 acc0 = {0.f, 0.f, 0.f, 0.f};
        f32x4 acc1 = {0.f, 0.f, 0.f, 0.f};

        const size_t gA = (size_t)(row0 + sar) * DIM + sak;
        uint4 pa = *reinterpret_cast<const uint4*>(Hin + gA);
        *reinterpret_cast<uint4*>(&A[0][sar][sak]) = pa;
        __syncthreads();
        int cur = 0;

        for (int it = 0; it < 32; ++it) {
            uint4 pn;
            if (it < 31)
                pn = *reinterpret_cast<const uint4*>(Hin + gA + (size_t)(it + 1) * BKP);
            const bf16x8 a0 = *reinterpret_cast<const bf16x8*>(&A[cur][am0][ka]);
            const bf16x8 a1 = *reinterpret_cast<const bf16x8*>(&A[cur][am1][ka]);
            const bf16x8 bh = *reinterpret_cast<const bf16x8*>(&Bh[bcol][it * BKP + ka]);
            const bf16x8 bl = *reinterpret_cast<const bf16x8*>(&Bl[bcol][it * BKP + ka]);
            acc0 = __builtin_amdgcn_mfma_f32_16x16x32_bf16(a0, bh, acc0, 0, 0, 0);
            acc1 = __builtin_amdgcn_mfma_f32_16x16x32_bf16(a1, bh, acc1, 0, 0, 0);
            acc0 = __builtin_amdgcn_mfma_f32_16x16x32_bf16(a0, bl, acc0, 0, 0, 0);
            acc1 = __builtin_amdgcn_mfma_f32_16x16x32_bf16(a1, bl, acc1, 0, 0, 0);
            if (it < 31) {
                *reinterpret_cast<uint4*>(&A[cur ^ 1][sar][sak]) = pn;
                __syncthreads();
                cur ^= 1;
            }
        }

        // ---- epilogue: tanh + H/out stores ----
#pragma unroll
        for (int f = 0; f < 2; ++f) {
#pragma unroll
            for (int r = 0; r < 4; ++r) {
                const int s = row0 + wm * 32 + f * 16 + (lane >> 4) * 4 + r;
                const int t = tt[f][r];
                const float a = (f == 0) ? acc0[r] : acc1[r];
                float h = 0.f;
                if (t >= 0) h = tanhf(a + xpv[f][r]);
                Hout[(size_t)s * DIM + colg] = f2bf(h);
                if (i >= WU) {
                    const int orow = (s >> 9) ? (SEQ + t) : t;
                    out[(size_t)orow * DIM + colg] = h;
                }
            }
        }

        // ---- device barrier (2-level, release/acquire) ----
        if (i < NSTEP - 1) {
            asm volatile("s_waitcnt vmcnt(0)" ::: "memory");
            __syncthreads();
            if (tid == 0) {
                __threadfence();   // release: wbl2 (H stores -> L3)
                __hip_atomic_fetch_add(&bar[grp * 16], 1u,
                                       __ATOMIC_RELAXED, __HIP_MEMORY_SCOPE_AGENT);
                if (blockIdx.x < 16) {   // group master
                    while (__hip_atomic_load(&bar[grp * 16], __ATOMIC_RELAXED,
                                             __HIP_MEMORY_SCOPE_AGENT) < 16u * (i + 1))
                        __builtin_amdgcn_s_sleep(1);
                    __hip_atomic_fetch_add(&bar[256], 1u,
                                           __ATOMIC_RELAXED, __HIP_MEMORY_SCOPE_AGENT);
                }
                while (__hip_atomic_load(&bar[256], __ATOMIC_RELAXED,
                                         __HIP_MEMORY_SCOPE_AGENT) < 16u * (i + 1))
                    __builtin_amdgcn_s_sleep(1);
                __threadfence();   // acquire: inv (Wh safe in LDS)
            }
            __syncthreads();
        }
    }
}

// ---------------------------------------------------------------------------
extern "C" void kernel_launch(void* const* d_in, const int* in_sizes, int n_in,
                              void* d_out, int out_size, void* d_ws, size_t ws_size,
                              hipStream_t stream)
{
    (void)in_sizes; (void)n_in; (void)out_size; (void)ws_size;
    const float* x  = (const float*)d_in[0];
    const float* Wx = (const float*)d_in[1];
    const float* Wh = (const float*)d_in[2];
    const float* b  = (const float*)d_in[3];
    float* out = (float*)d_out;

    char* ws = (char*)d_ws;
    const size_t MB = 1ull << 20;
    float*          xp   = (float*)ws;                        // [0, 64MB)
    unsigned short* WxTh = (unsigned short*)(ws + 64 * MB);
    unsigned short* WxTl = (unsigned short*)(ws + 66 * MB);
    unsigned short* WhTh = (unsigned short*)(ws + 68 * MB);
    unsigned short* WhTl = (unsigned short*)(ws + 70 * MB);
    unsigned short* H0   = (unsigned short*)(ws + 72 * MB);
    unsigned short* H1   = (unsigned short*)(ws + 74 * MB);
    unsigned int*   bar  = (unsigned int*)(ws + 76 * MB);     // 2KB counters

    unsigned short* xh = (unsigned short*)d_out;   // first 64MB of out, freed
    unsigned short* xl = xh + (size_t)SEQ * DIM;   // before steps write out

    hipLaunchKernelGGL(wsplit_kernel, dim3(256), dim3(256), 0, stream, Wx, WxTh, WxTl);
    hipLaunchKernelGGL(wsplit_kernel, dim3(256), dim3(256), 0, stream, Wh, WhTh, WhTl);
    hipLaunchKernelGGL(xsplit_kernel, dim3(2048), dim3(256), 0, stream, x, xh, xl);
    hipLaunchKernelGGL(xproj_mfma, dim3(2048), dim3(256), 0, stream,
                       xh, xl, WxTh, WxTl, b, xp);
    hipMemsetAsync(H0, 0, 2 * MB, stream);
    hipMemsetAsync(bar, 0, 2048, stream);

    void* args[] = {(void*)&H0, (void*)&H1, (void*)&xp,
                    (void*)&WhTh, (void*)&WhTl, (void*)&out, (void*)&bar};
    hipLaunchCooperativeKernel((void*)step_persist2, dim3(256), dim3(512),
                               args, 0, stream);
}